// Round 1
// baseline (4489.667 us; speedup 1.0000x reference)
//
#include <hip/hip_runtime.h>
#include <stdint.h>

// LSTM: BATCH=64, SEQ=512, INPUT=512, UNITS=512, gates order i,f,g,o.
// Strategy:
//   K0 (prep): x -> bf16 copy; Wx,Wh -> bf16 transposed [n][k]; H[0] <- h0 (packed bf16 pairs); zero barrier counters.
//   K1 (persistent recurrence): grid 256 wgs = 8 sample-groups (8 samples) x 32 unit-groups (16 units = 64 gate-cols).
//     Per wg: Wh/Wx column-slice fragments persistent in VGPRs (loaded once).
//     Per step: stage x_t + H(t-1) slices to LDS -> mfma 16x16x32 bf16 (M=16 pad of 8 samples) ->
//               z to LDS -> gates on 128 threads (c-state in registers) -> h to out + packed bf16 H ->
//               32-wg spin barrier per sample-group (agent-scope atomics, monotonic counter).

#define LSTM_NX   16777216LL   // 64*512*512

// ws byte offsets
#define OFF_XBF   0ull                    // bf16 x [64][512][512]  (32 MB)
#define OFF_WXT   33554432ull             // bf16 Wx^T [2048][512]  (2 MB)
#define OFF_WHT   35651584ull             // bf16 Wh^T [2048][512]  (2 MB)
#define OFF_H     37748736ull             // u32 H[2][64][256] packed bf16 pairs (128 KB)
#define OFF_CNT   37879808ull             // u32 cnt[8] (stride 64 u32 = 256 B)

typedef short short8 __attribute__((ext_vector_type(8)));
typedef float f32x4 __attribute__((ext_vector_type(4)));

__device__ __forceinline__ unsigned f32_to_bf16(float f) {
    union { float f; unsigned u; } v; v.f = f;
    unsigned u = v.u;
    unsigned r = u + 0x7FFFu + ((u >> 16) & 1u);   // RNE
    return r >> 16;
}

__global__ void prep_kernel(const float* __restrict__ x,
                            const float* __restrict__ h0,
                            const float* __restrict__ Wx,
                            const float* __restrict__ Wh,
                            unsigned char* __restrict__ ws) {
    long long i = (long long)blockIdx.x * blockDim.x + threadIdx.x;
    unsigned short* xbf = (unsigned short*)(ws + OFF_XBF);
    unsigned short* wxt = (unsigned short*)(ws + OFF_WXT);
    unsigned short* wht = (unsigned short*)(ws + OFF_WHT);
    unsigned* Hg  = (unsigned*)(ws + OFF_H);
    unsigned* cnt = (unsigned*)(ws + OFF_CNT);

    if (i < LSTM_NX) { xbf[i] = (unsigned short)f32_to_bf16(x[i]); return; }
    i -= LSTM_NX;
    if (i < 1048576) {              // Wx^T[n][k] = Wx[k][n]
        int n = (int)(i >> 9), k = (int)(i & 511);
        wxt[i] = (unsigned short)f32_to_bf16(Wx[(long long)k * 2048 + n]); return;
    }
    i -= 1048576;
    if (i < 1048576) {              // Wh^T[n][k] = Wh[k][n]
        int n = (int)(i >> 9), k = (int)(i & 511);
        wht[i] = (unsigned short)f32_to_bf16(Wh[(long long)k * 2048 + n]); return;
    }
    i -= 1048576;
    if (i < 16384) {                // H[0][b][pair] <- h0
        int b = (int)(i >> 8), p = (int)(i & 255);
        unsigned lo = f32_to_bf16(h0[b * 512 + 2 * p]);
        unsigned hi = f32_to_bf16(h0[b * 512 + 2 * p + 1]);
        Hg[(long long)b * 256 + p] = lo | (hi << 16); return;
    }
    i -= 16384;
    if (i < 8) cnt[i * 64] = 0;     // barrier counters
}

// LDS layout (bytes): xbuf [9][520]bf16 @0 (row 8 = zeros, pad row for M=16 tile)
//                     hbuf [9][520]bf16 @9360
//                     zbuf [2][8][68]f32 @18720  (kh plane, sample row, 64 cols + pad)
__launch_bounds__(256, 1)
__global__ void lstm_kernel(const float* __restrict__ c0,
                            const float* __restrict__ bias,
                            float* __restrict__ out,
                            unsigned char* __restrict__ ws) {
    const int tid  = threadIdx.x;
    const int bid  = blockIdx.x;
    const int s    = bid & 7;      // sample group: batches 8s..8s+7 (co-XCD heuristic)
    const int jg   = bid >> 3;     // unit group: units 16jg..16jg+15
    const int lane = tid & 63;
    const int wave = tid >> 6;
    const int nl   = lane & 15;
    const int q    = lane >> 4;
    const int kh   = wave & 1;     // K half (8 k-tiles each)
    const int ng   = wave >> 1;    // n group (32 of 64 cols)

    const unsigned short* xbf = (const unsigned short*)(ws + OFF_XBF);
    const unsigned short* wxt = (const unsigned short*)(ws + OFF_WXT);
    const unsigned short* wht = (const unsigned short*)(ws + OFF_WHT);
    unsigned* Hg  = (unsigned*)(ws + OFF_H);
    unsigned* cnt = (unsigned*)(ws + OFF_CNT) + s * 64;

    __shared__ __align__(16) unsigned char lds[23072];
    float* zb = (float*)(lds + 18720);

    // zero the pad rows (row 8 of xbuf and hbuf) once
    {
        unsigned* xr8 = (unsigned*)(lds + 8 * 1040);
        unsigned* hr8 = (unsigned*)(lds + 9360 + 8 * 1040);
        for (int idx = tid; idx < 520; idx += 256) {
            if (idx < 260) xr8[idx] = 0; else hr8[idx - 260] = 0;
        }
    }

    // persistent B fragments: B[k=q*8+j][n=lane&15] for each k-tile, from W^T[n][k] rows
    short8 fWh[2][8], fWx[2][8];
#pragma unroll
    for (int nti = 0; nti < 2; ++nti) {
        const int n = (ng * 2 + nti) * 512 + jg * 16 + nl;   // global gate-col (gate-major: gate = c>>4)
        const unsigned short* whp = wht + (long long)n * 512;
        const unsigned short* wxp = wxt + (long long)n * 512;
#pragma unroll
        for (int kt = 0; kt < 8; ++kt) {
            const int k0 = (kh * 8 + kt) * 32 + q * 8;
            fWh[nti][kt] = *(const short8*)(whp + k0);
            fWx[nti][kt] = *(const short8*)(wxp + k0);
        }
    }

    // gate-thread state (tid < 128): one (sample m, unit u) each
    const int gm  = tid >> 4;
    const int gu  = tid & 15;
    const int gb  = 8 * s + gm;
    const int gug = jg * 16 + gu;
    float creg = 0.f;
    float bv0 = 0.f, bv1 = 0.f, bv2 = 0.f, bv3 = 0.f;
    if (tid < 128) {
        creg = c0[gb * 512 + gug];
        bv0 = bias[0 * 512 + gug];
        bv1 = bias[1 * 512 + gug];
        bv2 = bias[2 * 512 + gug];
        bv3 = bias[3 * 512 + gug];
    }

    // staging map: thread -> (row sm = tid>>5, 32B chunk sc = tid&31) of the 8x512 slice
    const int sm = tid >> 5, sc = tid & 31;
    const int sb = 8 * s + sm;
    const unsigned* xsrc_base = (const unsigned*)xbf + (long long)sb * 512 * 256 + sc * 8;
    unsigned* hsrc_base = Hg + sb * 256 + sc * 8;
    uint4* xdst = (uint4*)(lds + sm * 1040 + sc * 32);
    uint4* hdst = (uint4*)(lds + 9360 + sm * 1040 + sc * 32);

    // A-fragment LDS read base: A[m=lane&15][k=q*8+j]; pad rows m>=8 -> zero row 8
    const int am = (nl < 8) ? nl : 8;
    const unsigned char* axp = lds + am * 1040 + q * 16;
    const unsigned char* ahp = lds + 9360 + am * 1040 + q * 16;

    for (int t = 0; t < 512; ++t) {
        const int rb = t & 1, wb = rb ^ 1;

        // ---- stage x_t and H(t-1) slices into LDS ----
        {
            const unsigned* xs = xsrc_base + t * 256;
            uint4 xv0 = *(const uint4*)(xs);
            uint4 xv1 = *(const uint4*)(xs + 4);
            const unsigned* hs = hsrc_base + rb * 16384;
            unsigned hv[8];
#pragma unroll
            for (int i2 = 0; i2 < 8; ++i2)
                hv[i2] = __hip_atomic_load(hs + i2, __ATOMIC_RELAXED, __HIP_MEMORY_SCOPE_AGENT);
            xdst[0] = xv0; xdst[1] = xv1;
            uint4 h0v; h0v.x = hv[0]; h0v.y = hv[1]; h0v.z = hv[2]; h0v.w = hv[3];
            uint4 h1v; h1v.x = hv[4]; h1v.y = hv[5]; h1v.z = hv[6]; h1v.w = hv[7];
            hdst[0] = h0v; hdst[1] = h1v;
        }
        __syncthreads();   // S1: staging complete

        // ---- MFMA: z-slice = x_t@Wx + h@Wh for (16-pad samples x 32 cols, K half) ----
        f32x4 accx0 = {0.f, 0.f, 0.f, 0.f}, accx1 = {0.f, 0.f, 0.f, 0.f};
        f32x4 acch0 = {0.f, 0.f, 0.f, 0.f}, acch1 = {0.f, 0.f, 0.f, 0.f};
#pragma unroll
        for (int kt = 0; kt < 8; ++kt) {
            const int kb = (kh * 8 + kt) * 64;   // byte offset along k
            short8 ax = *(const short8*)(axp + kb);
            short8 ah = *(const short8*)(ahp + kb);
            accx0 = __builtin_amdgcn_mfma_f32_16x16x32_bf16(ax, fWx[0][kt], accx0, 0, 0, 0);
            acch0 = __builtin_amdgcn_mfma_f32_16x16x32_bf16(ah, fWh[0][kt], acch0, 0, 0, 0);
            accx1 = __builtin_amdgcn_mfma_f32_16x16x32_bf16(ax, fWx[1][kt], accx1, 0, 0, 0);
            acch1 = __builtin_amdgcn_mfma_f32_16x16x32_bf16(ah, fWh[1][kt], acch1, 0, 0, 0);
        }
        // write z partials: D[m=q*4+r][n=lane&15]; only rows m<8 are real (q<2)
        if (q < 2) {
#pragma unroll
            for (int nti = 0; nti < 2; ++nti) {
                const int c = ng * 32 + nti * 16 + nl;
                f32x4 v = (nti == 0) ? (accx0 + acch0) : (accx1 + acch1);
#pragma unroll
                for (int r = 0; r < 4; ++r)
                    zb[kh * 544 + (q * 4 + r) * 68 + c] = v[r];
            }
        }
        __syncthreads();   // S2: z complete

        // ---- gates + state update + outputs ----
        if (tid < 128) {
            const float* zrow = zb + gm * 68;
            float z0 = zrow[0 * 16 + gu] + zrow[544 + 0 * 16 + gu] + bv0;
            float z1 = zrow[1 * 16 + gu] + zrow[544 + 1 * 16 + gu] + bv1;
            float z2 = zrow[2 * 16 + gu] + zrow[544 + 2 * 16 + gu] + bv2;
            float z3 = zrow[3 * 16 + gu] + zrow[544 + 3 * 16 + gu] + bv3;
            float ig = 1.f / (1.f + __expf(-z0));
            float fg = 1.f / (1.f + __expf(-z1));
            float gg = tanhf(z2);
            float og = 1.f / (1.f + __expf(-z3));
            float cn = fg * creg + ig * gg;
            creg = cn;
            float hn = og * tanhf(cn);
            out[(long long)t * 32768 + gb * 512 + gug] = hn;
            unsigned hb16 = f32_to_bf16(hn);
            unsigned other = (unsigned)__shfl((int)hb16, (lane + 1) & 63, 64);
            if ((gu & 1) == 0) {
                unsigned pk = hb16 | (other << 16);
                __hip_atomic_store(Hg + wb * 16384 + gb * 256 + (gug >> 1), pk,
                                   __ATOMIC_RELAXED, __HIP_MEMORY_SCOPE_AGENT);
            }
        }
        __syncthreads();   // S3: all H stores drained (vmcnt) before arrival

        // ---- 32-wg barrier per sample group (monotonic counter, no reset) ----
        if (tid == 0) {
            __hip_atomic_fetch_add(cnt, 1u, __ATOMIC_RELEASE, __HIP_MEMORY_SCOPE_AGENT);
            const unsigned target = 32u * (unsigned)(t + 1);
            while (__hip_atomic_load(cnt, __ATOMIC_ACQUIRE, __HIP_MEMORY_SCOPE_AGENT) < target)
                __builtin_amdgcn_s_sleep(1);
        }
        __syncthreads();   // S4: release whole wg
    }
}

extern "C" void kernel_launch(void* const* d_in, const int* in_sizes, int n_in,
                              void* d_out, int out_size, void* d_ws, size_t ws_size,
                              hipStream_t stream) {
    const float* x  = (const float*)d_in[0];
    const float* h0 = (const float*)d_in[1];
    const float* c0 = (const float*)d_in[2];
    const float* Wx = (const float*)d_in[3];
    const float* Wh = (const float*)d_in[4];
    const float* b  = (const float*)d_in[5];
    unsigned char* ws = (unsigned char*)d_ws;
    float* out = (float*)d_out;

    const long long n0 = LSTM_NX + 1048576 + 1048576 + 16384 + 8;
    const int blocks0 = (int)((n0 + 255) / 256);
    hipLaunchKernelGGL(prep_kernel, dim3(blocks0), dim3(256), 0, stream, x, h0, Wx, Wh, ws);
    hipLaunchKernelGGL(lstm_kernel, dim3(256), dim3(256), 0, stream, c0, b, out, ws);
}

// Round 2
// 3146.231 us; speedup vs baseline: 1.4270x; 1.4270x over previous
//
#include <hip/hip_runtime.h>
#include <stdint.h>

// LSTM: BATCH=64, SEQ=512, INPUT=512, UNITS=512, gates order i,f,g,o.
// Strategy:
//   K0 (prep): x -> bf16; Wx,Wh -> bf16 transposed [n][k]; H[0] <- h0 (packed bf16 pairs); zero flags.
//   K1 (persistent recurrence): grid 256 wgs = 8 sample-groups (8 samples) x 32 unit-groups (16 units).
//     Wh/Wx column-slice fragments persistent in registers (loaded once).
//     Per step: stage x_t (prefetched) + H(t-1) to LDS -> mfma 16x16x32 bf16 -> z to LDS ->
//               gates on 128 threads (c in regs) -> packed bf16 H store (agent-coherent) ->
//               per-wg FLAG STORE (own 64B line, release) -> out store -> wave0 polls 32 flags
//               (32 distinct lines, no RMW) -> __syncthreads release.

#define LSTM_NX   16777216LL   // 64*512*512

// ws byte offsets
#define OFF_XBF   0ull                    // bf16 x [64][512][512]  (32 MB)
#define OFF_WXT   33554432ull             // bf16 Wx^T [2048][512]  (2 MB)
#define OFF_WHT   35651584ull             // bf16 Wh^T [2048][512]  (2 MB)
#define OFF_H     37748736ull             // u32 H[2][64][256] packed bf16 pairs (128 KB)
#define OFF_FLG   37879808ull             // u32 flags[8][32], each on its own 64B line (16 KB)

typedef short short8 __attribute__((ext_vector_type(8)));
typedef float f32x4 __attribute__((ext_vector_type(4)));

__device__ __forceinline__ unsigned f32_to_bf16(float f) {
    union { float f; unsigned u; } v; v.f = f;
    unsigned u = v.u;
    unsigned r = u + 0x7FFFu + ((u >> 16) & 1u);   // RNE
    return r >> 16;
}

__global__ void prep_kernel(const float* __restrict__ x,
                            const float* __restrict__ h0,
                            const float* __restrict__ Wx,
                            const float* __restrict__ Wh,
                            unsigned char* __restrict__ ws) {
    long long i = (long long)blockIdx.x * blockDim.x + threadIdx.x;
    unsigned short* xbf = (unsigned short*)(ws + OFF_XBF);
    unsigned short* wxt = (unsigned short*)(ws + OFF_WXT);
    unsigned short* wht = (unsigned short*)(ws + OFF_WHT);
    unsigned* Hg  = (unsigned*)(ws + OFF_H);
    unsigned* flg = (unsigned*)(ws + OFF_FLG);

    if (i < LSTM_NX) { xbf[i] = (unsigned short)f32_to_bf16(x[i]); return; }
    i -= LSTM_NX;
    if (i < 1048576) {              // Wx^T[n][k] = Wx[k][n]
        int n = (int)(i >> 9), k = (int)(i & 511);
        wxt[i] = (unsigned short)f32_to_bf16(Wx[(long long)k * 2048 + n]); return;
    }
    i -= 1048576;
    if (i < 1048576) {              // Wh^T[n][k] = Wh[k][n]
        int n = (int)(i >> 9), k = (int)(i & 511);
        wht[i] = (unsigned short)f32_to_bf16(Wh[(long long)k * 2048 + n]); return;
    }
    i -= 1048576;
    if (i < 16384) {                // H[0][b][pair] <- h0
        int b = (int)(i >> 8), p = (int)(i & 255);
        unsigned lo = f32_to_bf16(h0[b * 512 + 2 * p]);
        unsigned hi = f32_to_bf16(h0[b * 512 + 2 * p + 1]);
        Hg[(long long)b * 256 + p] = lo | (hi << 16); return;
    }
    i -= 16384;
    if (i < 256) flg[i * 16] = 0;   // flags: one dword per 64B line
}

// LDS layout (bytes): xbuf [9][520]bf16 @0 (row 8 = zeros, pad row for M=16 tile)
//                     hbuf [9][520]bf16 @9360
//                     zbuf [2][8][68]f32 @18720  (kh plane, sample row, 64 cols + pad)
__launch_bounds__(256, 1)
__global__ void lstm_kernel(const float* __restrict__ c0,
                            const float* __restrict__ bias,
                            float* __restrict__ out,
                            unsigned char* __restrict__ ws) {
    const int tid  = threadIdx.x;
    const int bid  = blockIdx.x;
    const int s    = bid & 7;      // sample group: batches 8s..8s+7 (co-XCD heuristic)
    const int jg   = bid >> 3;     // unit group: units 16jg..16jg+15
    const int lane = tid & 63;
    const int wave = tid >> 6;
    const int nl   = lane & 15;
    const int q    = lane >> 4;
    const int kh   = wave & 1;     // K half (8 k-tiles each)
    const int ng   = wave >> 1;    // n group (32 of 64 cols)

    const unsigned short* xbf = (const unsigned short*)(ws + OFF_XBF);
    const unsigned short* wxt = (const unsigned short*)(ws + OFF_WXT);
    const unsigned short* wht = (const unsigned short*)(ws + OFF_WHT);
    unsigned* Hg   = (unsigned*)(ws + OFF_H);
    unsigned* flgG = (unsigned*)(ws + OFF_FLG) + s * 32 * 16;   // this group's 32 flag lines
    unsigned* flgMy = flgG + jg * 16;

    __shared__ __align__(16) unsigned char lds[23072];
    float* zb = (float*)(lds + 18720);

    // zero the pad rows (row 8 of xbuf and hbuf) once
    {
        unsigned* xr8 = (unsigned*)(lds + 8 * 1040);
        unsigned* hr8 = (unsigned*)(lds + 9360 + 8 * 1040);
        for (int idx = tid; idx < 520; idx += 256) {
            if (idx < 260) xr8[idx] = 0; else hr8[idx - 260] = 0;
        }
    }

    // persistent B fragments: B[k=q*8+j][n=lane&15] for each k-tile, from W^T[n][k] rows
    short8 fWh[2][8], fWx[2][8];
#pragma unroll
    for (int nti = 0; nti < 2; ++nti) {
        const int n = (ng * 2 + nti) * 512 + jg * 16 + nl;   // gate-major global col
        const unsigned short* whp = wht + (long long)n * 512;
        const unsigned short* wxp = wxt + (long long)n * 512;
#pragma unroll
        for (int kt = 0; kt < 8; ++kt) {
            const int k0 = (kh * 8 + kt) * 32 + q * 8;
            fWh[nti][kt] = *(const short8*)(whp + k0);
            fWx[nti][kt] = *(const short8*)(wxp + k0);
        }
    }

    // gate-thread state (tid < 128): one (sample m, unit u) each
    const int gm  = tid >> 4;
    const int gu  = tid & 15;
    const int gb  = 8 * s + gm;
    const int gug = jg * 16 + gu;
    float creg = 0.f;
    float bv0 = 0.f, bv1 = 0.f, bv2 = 0.f, bv3 = 0.f;
    if (tid < 128) {
        creg = c0[gb * 512 + gug];
        bv0 = bias[0 * 512 + gug];
        bv1 = bias[1 * 512 + gug];
        bv2 = bias[2 * 512 + gug];
        bv3 = bias[3 * 512 + gug];
    }

    // staging map: thread -> (row sm = tid>>5, 32B chunk sc = tid&31) of the 8x512 slice
    const int sm = tid >> 5, sc = tid & 31;
    const int sb = 8 * s + sm;
    const unsigned* xsrc_base = (const unsigned*)xbf + (long long)sb * 512 * 256 + sc * 8;
    unsigned* hsrc_base = Hg + sb * 256 + sc * 8;
    uint4* xdst = (uint4*)(lds + sm * 1040 + sc * 32);
    uint4* hdst = (uint4*)(lds + 9360 + sm * 1040 + sc * 32);

    // A-fragment LDS read base: A[m=lane&15][k=q*8+j]; pad rows m>=8 -> zero row 8
    const int am = (nl < 8) ? nl : 8;
    const unsigned char* axp = lds + am * 1040 + q * 16;
    const unsigned char* ahp = lds + 9360 + am * 1040 + q * 16;

    // x prefetch for t=0
    uint4 px0 = *(const uint4*)(xsrc_base);
    uint4 px1 = *(const uint4*)(xsrc_base + 4);

    for (int t = 0; t < 512; ++t) {
        const int rb = t & 1, wb = rb ^ 1;

        // ---- stage H(t-1) (coherent loads) and x_t (prefetched regs) into LDS ----
        {
            const unsigned* hs = hsrc_base + rb * 16384;
            unsigned hv[8];
#pragma unroll
            for (int i2 = 0; i2 < 8; ++i2)
                hv[i2] = __hip_atomic_load(hs + i2, __ATOMIC_RELAXED, __HIP_MEMORY_SCOPE_AGENT);
            xdst[0] = px0; xdst[1] = px1;
            uint4 h0v; h0v.x = hv[0]; h0v.y = hv[1]; h0v.z = hv[2]; h0v.w = hv[3];
            uint4 h1v; h1v.x = hv[4]; h1v.y = hv[5]; h1v.z = hv[6]; h1v.w = hv[7];
            hdst[0] = h0v; hdst[1] = h1v;
            // prefetch x for t+1 (stays within ws: reads roll into WXT region at t=511)
            const unsigned* xs = xsrc_base + (t + 1) * 256;
            px0 = *(const uint4*)(xs);
            px1 = *(const uint4*)(xs + 4);
        }
        __syncthreads();   // S1: staging complete

        // ---- MFMA: z-slice = x_t@Wx + h@Wh (16-pad samples x 32 cols, K half) ----
        f32x4 accx0 = {0.f, 0.f, 0.f, 0.f}, accx1 = {0.f, 0.f, 0.f, 0.f};
        f32x4 acch0 = {0.f, 0.f, 0.f, 0.f}, acch1 = {0.f, 0.f, 0.f, 0.f};
#pragma unroll
        for (int kt = 0; kt < 8; ++kt) {
            const int kb = (kh * 8 + kt) * 64;   // byte offset along k
            short8 ax = *(const short8*)(axp + kb);
            short8 ah = *(const short8*)(ahp + kb);
            accx0 = __builtin_amdgcn_mfma_f32_16x16x32_bf16(ax, fWx[0][kt], accx0, 0, 0, 0);
            acch0 = __builtin_amdgcn_mfma_f32_16x16x32_bf16(ah, fWh[0][kt], acch0, 0, 0, 0);
            accx1 = __builtin_amdgcn_mfma_f32_16x16x32_bf16(ax, fWx[1][kt], accx1, 0, 0, 0);
            acch1 = __builtin_amdgcn_mfma_f32_16x16x32_bf16(ah, fWh[1][kt], acch1, 0, 0, 0);
        }
        // write z partials: D[m=q*4+r][n=lane&15]; only rows m<8 real (q<2)
        if (q < 2) {
#pragma unroll
            for (int nti = 0; nti < 2; ++nti) {
                const int c = ng * 32 + nti * 16 + nl;
                f32x4 v = (nti == 0) ? (accx0 + acch0) : (accx1 + acch1);
#pragma unroll
                for (int r = 0; r < 4; ++r)
                    zb[kh * 544 + (q * 4 + r) * 68 + c] = v[r];
            }
        }
        __syncthreads();   // S2: z complete

        // ---- gates + state update + H publish ----
        float hn = 0.f;
        if (tid < 128) {
            const float* zrow = zb + gm * 68;
            float z0 = zrow[0 * 16 + gu] + zrow[544 + 0 * 16 + gu] + bv0;
            float z1 = zrow[1 * 16 + gu] + zrow[544 + 1 * 16 + gu] + bv1;
            float z2 = zrow[2 * 16 + gu] + zrow[544 + 2 * 16 + gu] + bv2;
            float z3 = zrow[3 * 16 + gu] + zrow[544 + 3 * 16 + gu] + bv3;
            float ig = __fdividef(1.f, 1.f + __expf(-z0));
            float fg = __fdividef(1.f, 1.f + __expf(-z1));
            float z2c = fminf(fmaxf(z2, -20.f), 20.f);
            float e2 = __expf(2.f * z2c);
            float gg = __fdividef(e2 - 1.f, e2 + 1.f);
            float og = __fdividef(1.f, 1.f + __expf(-z3));
            float cn = fg * creg + ig * gg;
            creg = cn;
            float cnc = fminf(fmaxf(cn, -20.f), 20.f);
            float ec = __expf(2.f * cnc);
            hn = og * __fdividef(ec - 1.f, ec + 1.f);
            unsigned hb16 = f32_to_bf16(hn);
            unsigned other = (unsigned)__shfl((int)hb16, (lane + 1) & 63, 64);
            if ((gu & 1) == 0) {
                unsigned pk = hb16 | (other << 16);
                __hip_atomic_store(Hg + wb * 16384 + gb * 256 + (gug >> 1), pk,
                                   __ATOMIC_RELAXED, __HIP_MEMORY_SCOPE_AGENT);
            }
        }
        __syncthreads();   // S3: every wave's H stores drained (per-wave vmcnt + barrier)

        // ---- publish our flag (own 64B line, no RMW anywhere) ----
        if (tid == 0)
            __hip_atomic_store(flgMy, (unsigned)(t + 1),
                               __ATOMIC_RELEASE, __HIP_MEMORY_SCOPE_AGENT);

        // out store AFTER flag: off the inter-wg critical path
        if (tid < 128)
            out[(long long)t * 32768 + gb * 512 + gug] = hn;

        // ---- wave 0 polls all 32 flags (32 distinct cache lines) ----
        if (wave == 0) {
            const unsigned target = (unsigned)(t + 1);
            const unsigned* fp = flgG + (lane & 31) * 16;
            for (;;) {
                unsigned v = (lane < 32)
                    ? __hip_atomic_load(fp, __ATOMIC_RELAXED, __HIP_MEMORY_SCOPE_AGENT)
                    : target;
                if (__all((int)(v >= target))) break;
                __builtin_amdgcn_s_sleep(1);
            }
        }
        __syncthreads();   // S4: release whole wg
    }
}

extern "C" void kernel_launch(void* const* d_in, const int* in_sizes, int n_in,
                              void* d_out, int out_size, void* d_ws, size_t ws_size,
                              hipStream_t stream) {
    const float* x  = (const float*)d_in[0];
    const float* h0 = (const float*)d_in[1];
    const float* c0 = (const float*)d_in[2];
    const float* Wx = (const float*)d_in[3];
    const float* Wh = (const float*)d_in[4];
    const float* b  = (const float*)d_in[5];
    unsigned char* ws = (unsigned char*)d_ws;
    float* out = (float*)d_out;

    const long long n0 = LSTM_NX + 1048576 + 1048576 + 16384 + 256;
    const int blocks0 = (int)((n0 + 255) / 256);
    hipLaunchKernelGGL(prep_kernel, dim3(blocks0), dim3(256), 0, stream, x, h0, Wx, Wh, ws);
    hipLaunchKernelGGL(lstm_kernel, dim3(256), dim3(256), 0, stream, c0, b, out, ws);
}

// Round 3
// 2216.433 us; speedup vs baseline: 2.0256x; 1.4195x over previous
//
#include <hip/hip_runtime.h>
#include <stdint.h>

// LSTM: BATCH=64, SEQ=512, INPUT=512, UNITS=512, gates i,f,g,o.
// R3: single-round-trip handoff. H published as atomic u64 = (epoch<<32)|bf16x2 pair.
// Consumers spin on the exact slots they stage -> no inter-wg barrier, no flags,
// no store-drain ordering. Only 2 intra-wg barriers/step. W fragments loaded once
// directly from f32 W (aligned 64B column strips), converted in-register.

#define LSTM_NX   16777216LL   // 64*512*512

// ws byte offsets
#define OFF_XBF   0ull                    // bf16 x [64][512][512]  (32 MB)
#define OFF_HU    33562624ull             // u64 H[2][64][256]: (tag<<32)|bf16pair (256 KB)

typedef short short8 __attribute__((ext_vector_type(8)));
typedef float f32x4 __attribute__((ext_vector_type(4)));

__device__ __forceinline__ unsigned f32_to_bf16(float f) {
    union { float f; unsigned u; } v; v.f = f;
    unsigned u = v.u;
    unsigned r = u + 0x7FFFu + ((u >> 16) & 1u);   // RNE
    return r >> 16;
}

__global__ void prep_kernel(const float* __restrict__ x,
                            const float* __restrict__ h0,
                            unsigned char* __restrict__ ws) {
    long long i = (long long)blockIdx.x * blockDim.x + threadIdx.x;
    if (i < 2097152) {   // x -> bf16, 8 elements/thread, fully vectorized
        const float4* xs = (const float4*)x + i * 2;
        float4 a = xs[0], b = xs[1];
        unsigned w0 = f32_to_bf16(a.x) | (f32_to_bf16(a.y) << 16);
        unsigned w1 = f32_to_bf16(a.z) | (f32_to_bf16(a.w) << 16);
        unsigned w2 = f32_to_bf16(b.x) | (f32_to_bf16(b.y) << 16);
        unsigned w3 = f32_to_bf16(b.z) | (f32_to_bf16(b.w) << 16);
        uint4 o; o.x = w0; o.y = w1; o.z = w2; o.w = w3;
        ((uint4*)(ws + OFF_XBF))[i] = o;
        return;
    }
    i -= 2097152;
    if (i < 16384) {     // H[0] <- h0, tag=1
        int b = (int)(i >> 8), p = (int)(i & 255);
        unsigned lo = f32_to_bf16(h0[b * 512 + 2 * p]);
        unsigned hi = f32_to_bf16(h0[b * 512 + 2 * p + 1]);
        unsigned long long v = (unsigned long long)(lo | (hi << 16))
                             | (1ull << 32);
        ((unsigned long long*)(ws + OFF_HU))[(long long)b * 256 + p] = v;
    }
}

// LDS layout (bytes): xbuf [9][520]bf16 @0 (row 8 zeros, M=16 pad)
//                     hbuf [9][520]bf16 @9360
//                     zbuf [2][8][68]f32 @18720
__launch_bounds__(256, 1)
__global__ void lstm_kernel(const float* __restrict__ c0,
                            const float* __restrict__ bias,
                            const float* __restrict__ Wx,
                            const float* __restrict__ Wh,
                            float* __restrict__ out,
                            unsigned char* __restrict__ ws) {
    const int tid  = threadIdx.x;
    const int bid  = blockIdx.x;
    const int s    = bid & 7;      // sample group: batches 8s..8s+7
    const int jg   = bid >> 3;     // unit group: units 16jg..16jg+15
    const int lane = tid & 63;
    const int wave = tid >> 6;
    const int nl   = lane & 15;
    const int q    = lane >> 4;
    const int kh   = wave & 1;     // K half
    const int ng   = wave >> 1;    // n half (32 of 64 gate-cols)

    const unsigned short* xbf = (const unsigned short*)(ws + OFF_XBF);
    unsigned long long* Hu = (unsigned long long*)(ws + OFF_HU);

    __shared__ __align__(16) unsigned char lds[23072];
    float* zb = (float*)(lds + 18720);

    // zero pad rows (row 8 of xbuf and hbuf) once
    {
        unsigned* xr8 = (unsigned*)(lds + 8 * 1040);
        unsigned* hr8 = (unsigned*)(lds + 9360 + 8 * 1040);
        for (int idx = tid; idx < 520; idx += 256) {
            if (idx < 260) xr8[idx] = 0; else hr8[idx - 260] = 0;
        }
    }

    // persistent B fragments, loaded ONCE straight from f32 W (bf16 RNE convert).
    // frag[j] = W[(k0+j)][n]; lanes nl=0..15 read 16 consecutive cols = one 64B line.
    short8 fWh[2][8], fWx[2][8];
#pragma unroll
    for (int nti = 0; nti < 2; ++nti) {
        const int n = (ng * 2 + nti) * 512 + jg * 16 + nl;   // gate-major col
#pragma unroll
        for (int kt = 0; kt < 8; ++kt) {
            const int k0 = (kh * 8 + kt) * 32 + q * 8;
            short8 vh, vx;
#pragma unroll
            for (int j = 0; j < 8; ++j) {
                vh[j] = (short)f32_to_bf16(Wh[(long long)(k0 + j) * 2048 + n]);
                vx[j] = (short)f32_to_bf16(Wx[(long long)(k0 + j) * 2048 + n]);
            }
            fWh[nti][kt] = vh; fWx[nti][kt] = vx;
        }
    }

    // gate-thread state (tid < 128): one (sample, unit) each
    const int gm  = tid >> 4;
    const int gu  = tid & 15;
    const int gb  = 8 * s + gm;
    const int gug = jg * 16 + gu;
    float creg = 0.f;
    float bv0 = 0.f, bv1 = 0.f, bv2 = 0.f, bv3 = 0.f;
    if (tid < 128) {
        creg = c0[gb * 512 + gug];
        bv0 = bias[0 * 512 + gug];
        bv1 = bias[1 * 512 + gug];
        bv2 = bias[2 * 512 + gug];
        bv3 = bias[3 * 512 + gug];
    }

    // staging map: thread -> (row sm, 8-pair chunk sc) of the 8x512 slice
    const int sm = tid >> 5, sc = tid & 31;
    const int sb = 8 * s + sm;
    const unsigned* xsrc_base = (const unsigned*)xbf + (long long)sb * 512 * 256 + sc * 8;
    unsigned long long* hsrc_base = Hu + sb * 256 + sc * 8;
    uint4* xdst = (uint4*)(lds + sm * 1040 + sc * 32);
    uint4* hdst = (uint4*)(lds + 9360 + sm * 1040 + sc * 32);

    // A-fragment LDS base: A[m=lane&15][k=q*8+j]; rows m>=8 -> zero row 8
    const int am = (nl < 8) ? nl : 8;
    const unsigned char* axp = lds + am * 1040 + q * 16;
    const unsigned char* ahp = lds + 9360 + am * 1040 + q * 16;

    // x prefetch for t=0
    uint4 px0 = *(const uint4*)(xsrc_base);
    uint4 px1 = *(const uint4*)(xsrc_base + 4);

    for (int t = 0; t < 512; ++t) {
        const int rb = t & 1, wb = rb ^ 1;

        // ---- x_t into LDS from prefetch regs; issue prefetch for t+1 ----
        xdst[0] = px0; xdst[1] = px1;
        {
            const int tp = (t + 1 < 512) ? (t + 1) : 511;
            const unsigned* xs = xsrc_base + tp * 256;
            px0 = *(const uint4*)(xs);
            px1 = *(const uint4*)(xs + 4);
        }

        // ---- spin on my 8 H slots until epoch == t+1; data+flag in one word ----
        {
            unsigned long long* hs = hsrc_base + rb * 16384;
            const unsigned tag = (unsigned)(t + 1);
            unsigned long long hv[8];
            for (;;) {
#pragma unroll
                for (int i2 = 0; i2 < 8; ++i2)
                    hv[i2] = __hip_atomic_load(hs + i2, __ATOMIC_RELAXED,
                                               __HIP_MEMORY_SCOPE_AGENT);
                unsigned bad = 0;
#pragma unroll
                for (int i2 = 0; i2 < 8; ++i2)
                    bad |= ((unsigned)(hv[i2] >> 32)) ^ tag;
                if (!bad) break;
                __builtin_amdgcn_s_sleep(0);
            }
            uint4 h0v, h1v;
            h0v.x = (unsigned)hv[0]; h0v.y = (unsigned)hv[1];
            h0v.z = (unsigned)hv[2]; h0v.w = (unsigned)hv[3];
            h1v.x = (unsigned)hv[4]; h1v.y = (unsigned)hv[5];
            h1v.z = (unsigned)hv[6]; h1v.w = (unsigned)hv[7];
            hdst[0] = h0v; hdst[1] = h1v;
        }
        __syncthreads();   // S1: staging complete

        // ---- MFMA: z-slice = x_t@Wx + h@Wh ----
        f32x4 accx0 = {0.f, 0.f, 0.f, 0.f}, accx1 = {0.f, 0.f, 0.f, 0.f};
        f32x4 acch0 = {0.f, 0.f, 0.f, 0.f}, acch1 = {0.f, 0.f, 0.f, 0.f};
#pragma unroll
        for (int kt = 0; kt < 8; ++kt) {
            const int kb = (kh * 8 + kt) * 64;
            short8 ax = *(const short8*)(axp + kb);
            short8 ah = *(const short8*)(ahp + kb);
            accx0 = __builtin_amdgcn_mfma_f32_16x16x32_bf16(ax, fWx[0][kt], accx0, 0, 0, 0);
            acch0 = __builtin_amdgcn_mfma_f32_16x16x32_bf16(ah, fWh[0][kt], acch0, 0, 0, 0);
            accx1 = __builtin_amdgcn_mfma_f32_16x16x32_bf16(ax, fWx[1][kt], accx1, 0, 0, 0);
            acch1 = __builtin_amdgcn_mfma_f32_16x16x32_bf16(ah, fWh[1][kt], acch1, 0, 0, 0);
        }
        if (q < 2) {   // D[m=q*4+r][n=lane&15]; rows m<8 real
#pragma unroll
            for (int nti = 0; nti < 2; ++nti) {
                const int c = ng * 32 + nti * 16 + nl;
                f32x4 v = (nti == 0) ? (accx0 + acch0) : (accx1 + acch1);
#pragma unroll
                for (int r = 0; r < 4; ++r)
                    zb[kh * 544 + (q * 4 + r) * 68 + c] = v[r];
            }
        }
        __syncthreads();   // S2: z complete

        // ---- gates + state + publish (no barrier after: dataflow sync) ----
        if (tid < 128) {
            const float* zrow = zb + gm * 68;
            float z0 = zrow[0 * 16 + gu] + zrow[544 + 0 * 16 + gu] + bv0;
            float z1 = zrow[1 * 16 + gu] + zrow[544 + 1 * 16 + gu] + bv1;
            float z2 = zrow[2 * 16 + gu] + zrow[544 + 2 * 16 + gu] + bv2;
            float z3 = zrow[3 * 16 + gu] + zrow[544 + 3 * 16 + gu] + bv3;
            float ig = __fdividef(1.f, 1.f + __expf(-z0));
            float fg = __fdividef(1.f, 1.f + __expf(-z1));
            float z2c = fminf(fmaxf(z2, -20.f), 20.f);
            float e2 = __expf(2.f * z2c);
            float gg = __fdividef(e2 - 1.f, e2 + 1.f);
            float og = __fdividef(1.f, 1.f + __expf(-z3));
            float cn = fg * creg + ig * gg;
            creg = cn;
            float cnc = fminf(fmaxf(cn, -20.f), 20.f);
            float ec = __expf(2.f * cnc);
            float hn = og * __fdividef(ec - 1.f, ec + 1.f);
            unsigned hb16 = f32_to_bf16(hn);
            unsigned other = (unsigned)__shfl((int)hb16, (lane + 1) & 63, 64);
            if ((gu & 1) == 0) {
                unsigned long long v = (unsigned long long)(hb16 | (other << 16))
                                     | ((unsigned long long)(unsigned)(t + 2) << 32);
                __hip_atomic_store(Hu + wb * 16384 + gb * 256 + (gug >> 1), v,
                                   __ATOMIC_RELAXED, __HIP_MEMORY_SCOPE_AGENT);
            }
            out[(long long)t * 32768 + gb * 512 + gug] = hn;
        }
        // next iteration's spin provides all ordering; S1 protects LDS reuse.
    }
}

extern "C" void kernel_launch(void* const* d_in, const int* in_sizes, int n_in,
                              void* d_out, int out_size, void* d_ws, size_t ws_size,
                              hipStream_t stream) {
    const float* x  = (const float*)d_in[0];
    const float* h0 = (const float*)d_in[1];
    const float* c0 = (const float*)d_in[2];
    const float* Wx = (const float*)d_in[3];
    const float* Wh = (const float*)d_in[4];
    const float* b  = (const float*)d_in[5];
    unsigned char* ws = (unsigned char*)d_ws;
    float* out = (float*)d_out;

    const long long n0 = 2097152 + 16384;
    const int blocks0 = (int)((n0 + 255) / 256);
    hipLaunchKernelGGL(prep_kernel, dim3(blocks0), dim3(256), 0, stream, x, h0, ws);
    hipLaunchKernelGGL(lstm_kernel, dim3(256), dim3(256), 0, stream,
                       c0, b, Wx, Wh, out, ws);
}

// Round 4
// 1739.902 us; speedup vs baseline: 2.5804x; 1.2739x over previous
//
#include <hip/hip_runtime.h>
#include <stdint.h>

// LSTM: BATCH=64, SEQ=512, INPUT=512, UNITS=512, gates i,f,g,o.
// R4: critical chain = h-MFMA -> in-register gate fusion -> tagged publish -> spin.
// x@Wx is computed for t+1 AFTER publishing h(t) (hidden under the spin wait).
// Columns per wave = all 4 gates x 4 units (full K) so gates fuse via 4 shfl
// gathers -- no z LDS round trip, no S2. A-operand LDS reads masked to real
// rows (nl<8). Out stores batched via 4KB LDS ring, burst every 8 steps.

#define OFF_XBF   0ull                    // bf16 x [64][512][512]  (32 MB)
#define OFF_HU    33562624ull             // u64 H[2][64][256]: (tag<<32)|bf16pair

typedef short short8 __attribute__((ext_vector_type(8)));
typedef float f32x4 __attribute__((ext_vector_type(4)));

__device__ __forceinline__ unsigned f32_to_bf16(float f) {
    union { float f; unsigned u; } v; v.f = f;
    unsigned u = v.u;
    unsigned r = u + 0x7FFFu + ((u >> 16) & 1u);   // RNE
    return r >> 16;
}

__global__ void prep_kernel(const float* __restrict__ x,
                            const float* __restrict__ h0,
                            unsigned char* __restrict__ ws) {
    long long i = (long long)blockIdx.x * blockDim.x + threadIdx.x;
    if (i < 2097152) {   // x -> bf16, 8 elements/thread
        const float4* xs = (const float4*)x + i * 2;
        float4 a = xs[0], b = xs[1];
        unsigned w0 = f32_to_bf16(a.x) | (f32_to_bf16(a.y) << 16);
        unsigned w1 = f32_to_bf16(a.z) | (f32_to_bf16(a.w) << 16);
        unsigned w2 = f32_to_bf16(b.x) | (f32_to_bf16(b.y) << 16);
        unsigned w3 = f32_to_bf16(b.z) | (f32_to_bf16(b.w) << 16);
        uint4 o; o.x = w0; o.y = w1; o.z = w2; o.w = w3;
        ((uint4*)(ws + OFF_XBF))[i] = o;
        return;
    }
    i -= 2097152;
    if (i < 16384) {     // H[0] <- h0, tag=1
        int b = (int)(i >> 8), p = (int)(i & 255);
        unsigned lo = f32_to_bf16(h0[b * 512 + 2 * p]);
        unsigned hi = f32_to_bf16(h0[b * 512 + 2 * p + 1]);
        ((unsigned long long*)(ws + OFF_HU))[(long long)b * 256 + p] =
            (unsigned long long)(lo | (hi << 16)) | (1ull << 32);
    }
}

// LDS: xbuf [8][1040B] @0, hbuf [8][1040B] @8320, out-ring [8][8][16]f32 @16640 (4KB)
__launch_bounds__(256, 1)
__global__ void lstm_kernel(const float* __restrict__ c0,
                            const float* __restrict__ bias,
                            const float* __restrict__ Wx,
                            const float* __restrict__ Wh,
                            float* __restrict__ out,
                            unsigned char* __restrict__ ws) {
    const int tid  = threadIdx.x;
    const int bid  = blockIdx.x;
    const int s    = bid & 7;      // sample group: batches 8s..8s+7
    const int jg   = bid >> 3;     // unit group: units 16jg..16jg+15
    const int lane = tid & 63;
    const int wave = tid >> 6;
    const int nl   = lane & 15;
    const int q    = lane >> 4;
    const int up   = nl & 3;       // unit-in-wave 0..3
    const int g    = nl >> 2;      // gate slot 0..3

    const unsigned short* xbf = (const unsigned short*)(ws + OFF_XBF);
    unsigned long long* Hu = (unsigned long long*)(ws + OFF_HU);

    __shared__ __align__(16) unsigned char lds[20736];
    float* lds_out = (float*)(lds + 16640);

    // persistent fragments: this wave covers cols {g*512 + jg*16 + wave*4 + up},
    // i.e. all 4 gates of 4 units, full K. B[n=lane&15][k=q*8+j] per k-tile.
    const int ncol = g * 512 + jg * 16 + wave * 4 + up;
    short8 fWh[16], fWx[16];
#pragma unroll
    for (int kt = 0; kt < 16; ++kt) {
        const int k0 = kt * 32 + q * 8;
        short8 vh, vx;
#pragma unroll
        for (int j = 0; j < 8; ++j) {
            vh[j] = (short)f32_to_bf16(Wh[(long long)(k0 + j) * 2048 + ncol]);
            vx[j] = (short)f32_to_bf16(Wx[(long long)(k0 + j) * 2048 + ncol]);
        }
        fWh[kt] = vh; fWx[kt] = vx;
    }

    const int ub = jg * 16 + wave * 4 + up;     // this lane's unit (global)
    const float bi  = bias[ub];
    const float bf_ = bias[512 + ub];
    const float bg  = bias[1024 + ub];
    const float bo  = bias[1536 + ub];

    float cr[4];
#pragma unroll
    for (int r = 0; r < 4; ++r) {
        const int m = q * 4 + r;
        cr[r] = (q < 2) ? c0[(8 * s + m) * 512 + ub] : 0.f;
    }

    // staging map: thread -> (row sm, 64B chunk sc) of the 8x512 slice
    const int sm = tid >> 5, sc = tid & 31;
    const int sb = 8 * s + sm;
    const unsigned* xsrc_base = (const unsigned*)xbf + (long long)sb * 131072 + sc * 8;
    unsigned long long* hsrc_base = Hu + sb * 256 + sc * 8;
    uint4* xdst = (uint4*)(lds + sm * 1040 + sc * 32);
    uint4* hdst = (uint4*)(lds + 8320 + sm * 1040 + sc * 32);

    // A-fragment read base (only lanes nl<8 read; others feed zero frags)
    const unsigned char* axp = lds + nl * 1040 + q * 16;
    const unsigned char* ahp = lds + 8320 + nl * 1040 + q * 16;
    const short8 zfrag = {0, 0, 0, 0, 0, 0, 0, 0};

    // shfl source lanes for gate gather (same q, same up, gate slot varies)
    const int gbase = (lane & 0x30) | (lane & 3);
    const int sl0 = gbase, sl1 = gbase | 4, sl2 = gbase | 8, sl3 = gbase | 12;

    // ---- prologue: stage x(0), accx = x(0)@Wx, stage h0 ----
    uint4 px0 = *(const uint4*)(xsrc_base);
    uint4 px1 = *(const uint4*)(xsrc_base + 4);
    xdst[0] = px0; xdst[1] = px1;
    px0 = *(const uint4*)(xsrc_base + 256);
    px1 = *(const uint4*)(xsrc_base + 256 + 4);
    __syncthreads();

    f32x4 accx;
    {
        f32x4 a0 = {0.f,0.f,0.f,0.f}, a1 = {0.f,0.f,0.f,0.f};
#pragma unroll
        for (int kt = 0; kt < 16; kt += 2) {
            short8 v0 = (nl < 8) ? *(const short8*)(axp + kt * 64) : zfrag;
            short8 v1 = (nl < 8) ? *(const short8*)(axp + kt * 64 + 64) : zfrag;
            a0 = __builtin_amdgcn_mfma_f32_16x16x32_bf16(v0, fWx[kt], a0, 0, 0, 0);
            a1 = __builtin_amdgcn_mfma_f32_16x16x32_bf16(v1, fWx[kt + 1], a1, 0, 0, 0);
        }
        accx = a0 + a1;
    }
    {   // spin h0 (tag 1, buffer 0) and stage
        unsigned long long hv[8];
        for (;;) {
#pragma unroll
            for (int i2 = 0; i2 < 8; ++i2)
                hv[i2] = __hip_atomic_load(hsrc_base + i2, __ATOMIC_RELAXED,
                                           __HIP_MEMORY_SCOPE_AGENT);
            unsigned bad = 0;
#pragma unroll
            for (int i2 = 0; i2 < 8; ++i2)
                bad |= ((unsigned)(hv[i2] >> 32)) ^ 1u;
            if (!bad) break;
            __builtin_amdgcn_s_sleep(0);
        }
        uint4 h0v, h1v;
        h0v.x = (unsigned)hv[0]; h0v.y = (unsigned)hv[1];
        h0v.z = (unsigned)hv[2]; h0v.w = (unsigned)hv[3];
        h1v.x = (unsigned)hv[4]; h1v.y = (unsigned)hv[5];
        h1v.z = (unsigned)hv[6]; h1v.w = (unsigned)hv[7];
        hdst[0] = h0v; hdst[1] = h1v;
    }
    __syncthreads();

    for (int t = 0; t < 512; ++t) {
        const int wb = (t + 1) & 1;

        // ---- 1: acch = h(t-1)@Wh  [critical chain] ----
        f32x4 acch;
        {
            f32x4 a0 = {0.f,0.f,0.f,0.f}, a1 = {0.f,0.f,0.f,0.f};
#pragma unroll
            for (int kt = 0; kt < 16; kt += 2) {
                short8 v0 = (nl < 8) ? *(const short8*)(ahp + kt * 64) : zfrag;
                short8 v1 = (nl < 8) ? *(const short8*)(ahp + kt * 64 + 64) : zfrag;
                a0 = __builtin_amdgcn_mfma_f32_16x16x32_bf16(v0, fWh[kt], a0, 0, 0, 0);
                a1 = __builtin_amdgcn_mfma_f32_16x16x32_bf16(v1, fWh[kt + 1], a1, 0, 0, 0);
            }
            acch = a0 + a1;
        }

        // ---- 2: gate fusion in registers (4 shfl gathers per row) ----
        float hn[4]; unsigned hb[4];
#pragma unroll
        for (int r = 0; r < 4; ++r) {
            float zs = accx[r] + acch[r];
            float z0 = __shfl(zs, sl0, 64) + bi;
            float z1 = __shfl(zs, sl1, 64) + bf_;
            float z2 = __shfl(zs, sl2, 64) + bg;
            float z3 = __shfl(zs, sl3, 64) + bo;
            float ig = __fdividef(1.f, 1.f + __expf(-z0));
            float fg = __fdividef(1.f, 1.f + __expf(-z1));
            float z2c = fminf(fmaxf(z2, -20.f), 20.f);
            float e2 = __expf(2.f * z2c);
            float gg = __fdividef(e2 - 1.f, e2 + 1.f);
            float og = __fdividef(1.f, 1.f + __expf(-z3));
            float cn = fg * cr[r] + ig * gg;
            cr[r] = cn;
            float cnc = fminf(fmaxf(cn, -20.f), 20.f);
            float ec = __expf(2.f * cnc);
            hn[r] = og * __fdividef(ec - 1.f, ec + 1.f);
            hb[r] = f32_to_bf16(hn[r]);
        }
        unsigned oth[4];
#pragma unroll
        for (int r = 0; r < 4; ++r)
            oth[r] = (unsigned)__shfl((int)hb[r], lane ^ 1, 64);

        // ---- 3: publish h(t) (end of chain head) + out-ring write ----
        if (q < 2 && g == 0) {
#pragma unroll
            for (int r = 0; r < 4; ++r)
                lds_out[(t & 7) * 128 + (q * 4 + r) * 16 + wave * 4 + up] = hn[r];
            if ((up & 1) == 0) {
#pragma unroll
                for (int r = 0; r < 4; ++r) {
                    unsigned long long v = (unsigned long long)(hb[r] | (oth[r] << 16))
                                         | ((unsigned long long)(unsigned)(t + 2) << 32);
                    __hip_atomic_store(Hu + (size_t)wb * 16384 + (8 * s + q * 4 + r) * 256
                                           + jg * 8 + wave * 2 + (up >> 1),
                                       v, __ATOMIC_RELAXED, __HIP_MEMORY_SCOPE_AGENT);
                }
            }
        }

        // ---- 4: stage x(t+1) from prefetch; issue prefetch t+2 [off-chain] ----
        xdst[0] = px0; xdst[1] = px1;
        {
            const int tp = (t + 2 < 512) ? (t + 2) : 511;
            px0 = *(const uint4*)(xsrc_base + tp * 256);
            px1 = *(const uint4*)(xsrc_base + tp * 256 + 4);
        }
        __syncthreads();   // S0

        // out burst every 8 steps (coalesced float4)
        if ((t & 7) == 7) {
            const int stp = tid >> 5, brow = (tid >> 2) & 7, qd = tid & 3;
            float4 v = *(const float4*)(lds_out + stp * 128 + brow * 16 + qd * 4);
            *(float4*)(out + (long long)(t - 7 + stp) * 32768
                           + (8 * s + brow) * 512 + jg * 16 + qd * 4) = v;
        }

        // ---- 5: accx = x(t+1)@Wx [hidden under spin] ----
        {
            f32x4 a0 = {0.f,0.f,0.f,0.f}, a1 = {0.f,0.f,0.f,0.f};
#pragma unroll
            for (int kt = 0; kt < 16; kt += 2) {
                short8 v0 = (nl < 8) ? *(const short8*)(axp + kt * 64) : zfrag;
                short8 v1 = (nl < 8) ? *(const short8*)(axp + kt * 64 + 64) : zfrag;
                a0 = __builtin_amdgcn_mfma_f32_16x16x32_bf16(v0, fWx[kt], a0, 0, 0, 0);
                a1 = __builtin_amdgcn_mfma_f32_16x16x32_bf16(v1, fWx[kt + 1], a1, 0, 0, 0);
            }
            accx = a0 + a1;
        }

        // ---- 6: spin on h(t) tags; stage into hbuf ----
        {
            unsigned long long* hs = hsrc_base + (size_t)wb * 16384;
            const unsigned tag = (unsigned)(t + 2);
            unsigned long long hv[8];
            for (;;) {
#pragma unroll
                for (int i2 = 0; i2 < 8; ++i2)
                    hv[i2] = __hip_atomic_load(hs + i2, __ATOMIC_RELAXED,
                                               __HIP_MEMORY_SCOPE_AGENT);
                unsigned bad = 0;
#pragma unroll
                for (int i2 = 0; i2 < 8; ++i2)
                    bad |= ((unsigned)(hv[i2] >> 32)) ^ tag;
                if (!bad) break;
                __builtin_amdgcn_s_sleep(0);
            }
            uint4 h0v, h1v;
            h0v.x = (unsigned)hv[0]; h0v.y = (unsigned)hv[1];
            h0v.z = (unsigned)hv[2]; h0v.w = (unsigned)hv[3];
            h1v.x = (unsigned)hv[4]; h1v.y = (unsigned)hv[5];
            h1v.z = (unsigned)hv[6]; h1v.w = (unsigned)hv[7];
            hdst[0] = h0v; hdst[1] = h1v;
        }
        __syncthreads();   // S1
    }
}

extern "C" void kernel_launch(void* const* d_in, const int* in_sizes, int n_in,
                              void* d_out, int out_size, void* d_ws, size_t ws_size,
                              hipStream_t stream) {
    const float* x  = (const float*)d_in[0];
    const float* h0 = (const float*)d_in[1];
    const float* c0 = (const float*)d_in[2];
    const float* Wx = (const float*)d_in[3];
    const float* Wh = (const float*)d_in[4];
    const float* b  = (const float*)d_in[5];
    unsigned char* ws = (unsigned char*)d_ws;
    float* out = (float*)d_out;

    const long long n0 = 2097152 + 16384;
    const int blocks0 = (int)((n0 + 255) / 256);
    hipLaunchKernelGGL(prep_kernel, dim3(blocks0), dim3(256), 0, stream, x, h0, ws);
    hipLaunchKernelGGL(lstm_kernel, dim3(256), dim3(256), 0, stream,
                       c0, b, Wx, Wh, out, ws);
}